// Round 1
// baseline (1145.837 us; speedup 1.0000x reference)
//
#include <hip/hip_runtime.h>

#define BB 32
#define NN 256
#define NF 16
#define NL 3

// ws layout (floats):
//   x0 : [B][N][4]  @ 0        (32768)
//   x1 : [B][N][4]  @ 32768
//   h0 : [B][N][16] @ 65536    (131072)
//   h1 : [B][N][16] @ 196608

__global__ __launch_bounds__(256)
void init_kernel(const float* __restrict__ xs, const float* __restrict__ charges,
                 const float* __restrict__ W_in, const float* __restrict__ b_in,
                 float* __restrict__ x0, float* __restrict__ h0) {
    int n = blockIdx.x * blockDim.x + threadIdx.x;   // 0..B*N-1
    if (n >= BB * NN) return;
    float c = charges[n];
#pragma unroll
    for (int f = 0; f < NF; ++f) {
        h0[n * NF + f] = fmaxf(fmaf(c, W_in[f], b_in[f]), 0.f);
    }
    x0[n * 4 + 0] = xs[n * 3 + 0];
    x0[n * 4 + 1] = xs[n * 3 + 1];
    x0[n * 4 + 2] = xs[n * 3 + 2];
    x0[n * 4 + 3] = 0.f;
}

__global__ __launch_bounds__(256, 2)
void layer_kernel(const float* __restrict__ x_in, const float* __restrict__ h_in,
                  float* __restrict__ x_out, float* __restrict__ h_out,
                  const float* __restrict__ vs,
                  const float* __restrict__ W_v, const float* __restrict__ We1,
                  const float* __restrict__ be1, const float* __restrict__ We2,
                  const float* __restrict__ be2, const float* __restrict__ Wx,
                  const float* __restrict__ Wh1, const float* __restrict__ bh1,
                  int l, int final_layer) {
    __shared__ float4 sx[NN];                       // 4 KB
    __shared__ float  sh[NN][NF + 1];               // 17 KB (padded rows)
    __shared__ float  su[NF][NN];                   // 16 KB, u transposed: su[k][i]
    __shared__ float  svd[16][NF];                  // 1 KB
    __shared__ __align__(16) float sWe2[NF][NF];    // 1 KB
    __shared__ float  sWsrc[NF][NF];                // 1 KB
    __shared__ float  sWdst[NF][NF];                // 1 KB
    __shared__ float  sWh1[2 * NF][NF];             // 2 KB
    __shared__ float  swr[NF], sbe1[NF], sbe2[NF], sWx[NF], sbh1[NF], sWv[NF];

    const int tid   = threadIdx.x;
    const int b     = blockIdx.x >> 4;
    const int chunk = blockIdx.x & 15;
    const int dst0  = chunk * 16;
    const int d     = tid >> 4;      // dst-local 0..15
    const int sl    = tid & 15;      // src lane 0..15
    const int j     = dst0 + d;      // this thread's dst node

    // ---- stage x, h, weights into LDS ----
    const float* xbp = x_in + (size_t)b * NN * 4;
    const float* hbp = h_in + (size_t)b * NN * NF;
    sx[tid] = ((const float4*)xbp)[tid];
    {
        const float4* h4 = (const float4*)hbp;
#pragma unroll
        for (int q = 0; q < 4; ++q) {
            float4 v = h4[tid * 4 + q];
            sh[tid][q * 4 + 0] = v.x;
            sh[tid][q * 4 + 1] = v.y;
            sh[tid][q * 4 + 2] = v.z;
            sh[tid][q * 4 + 3] = v.w;
        }
    }
    const float* pWe1 = We1 + l * (2 * NF + 1) * NF;
    ((float*)sWsrc)[tid] = pWe1[tid];
    ((float*)sWdst)[tid] = pWe1[256 + tid];
    ((float*)sWe2)[tid]  = We2[l * 256 + tid];
    ((float*)sWh1)[tid]        = Wh1[l * 512 + tid];
    ((float*)sWh1)[256 + tid]  = Wh1[l * 512 + 256 + tid];
    if (tid < NF) {
        swr[tid]  = pWe1[512 + tid];
        sbe1[tid] = be1[l * NF + tid];
        sbe2[tid] = be2[l * NF + tid];
        sWx[tid]  = Wx[l * NF + tid];
        sbh1[tid] = bh1[l * NF + tid];
        sWv[tid]  = W_v[l * NF + tid];
    }
    __syncthreads();

    // ---- precompute u_i = h_i @ Wsrc (thread t -> node t), store transposed ----
    {
        float hc[NF];
#pragma unroll
        for (int c = 0; c < NF; ++c) hc[c] = sh[tid][c];
#pragma unroll
        for (int k = 0; k < NF; ++k) {
            float u = 0.f;
#pragma unroll
            for (int c = 0; c < NF; ++c) u = fmaf(hc[c], sWsrc[c][k], u);
            su[k][tid] = u;
        }
    }
    // ---- precompute v_j = be1 + h_j @ Wdst for this block's 16 dsts ----
    {
        int jd = tid >> 4, k = tid & 15;
        int jj = dst0 + jd;
        float v = sbe1[k];
#pragma unroll
        for (int c = 0; c < NF; ++c) v = fmaf(sh[jj][c], sWdst[c][k], v);
        svd[jd][k] = v;
    }
    __syncthreads();

    float vreg[NF], wrreg[NF];
#pragma unroll
    for (int k = 0; k < NF; ++k) { vreg[k] = svd[d][k]; wrreg[k] = swr[k]; }
    const float4 xj = sx[j];

    float aggm[NF];
#pragma unroll
    for (int o = 0; o < NF; ++o) aggm[o] = 0.f;
    float ax = 0.f, ay = 0.f, az = 0.f;

    const float4* We2v = (const float4*)sWe2;

    // ---- edge loop: 16 srcs per thread, unrolled 4 at a time ----
    for (int ii = 0; ii < 4; ++ii) {
        const int s0 = sl + 64 * ii;
        const int s1 = s0 + 16, s2 = s0 + 32, s3 = s0 + 48;
        float4 xa = sx[s0], xb4 = sx[s1], xc4 = sx[s2], xd4 = sx[s3];
        float dax = xj.x - xa.x,  day = xj.y - xa.y,  daz = xj.z - xa.z;
        float dbx = xj.x - xb4.x, dby = xj.y - xb4.y, dbz = xj.z - xb4.z;
        float dcx = xj.x - xc4.x, dcy = xj.y - xc4.y, dcz = xj.z - xc4.z;
        float ddx = xj.x - xd4.x, ddy = xj.y - xd4.y, ddz = xj.z - xd4.z;
        float r2a = fmaf(dax, dax, fmaf(day, day, daz * daz));
        float r2b = fmaf(dbx, dbx, fmaf(dby, dby, dbz * dbz));
        float r2c = fmaf(dcx, dcx, fmaf(dcy, dcy, dcz * dcz));
        float r2d = fmaf(ddx, ddx, fmaf(ddy, ddy, ddz * ddz));
        float vala = (s0 != j) ? 1.f : 0.f;
        float valb = (s1 != j) ? 1.f : 0.f;
        float valc = (s2 != j) ? 1.f : 0.f;
        float vald = (s3 != j) ? 1.f : 0.f;

        float ma[NF], mb[NF], mc[NF], md[NF];
#pragma unroll
        for (int o = 0; o < NF; ++o) {
            float be = sbe2[o];
            ma[o] = be; mb[o] = be; mc[o] = be; md[o] = be;
        }
#pragma unroll
        for (int k = 0; k < NF; ++k) {
            float ua = su[k][s0], ub = su[k][s1], uc = su[k][s2], ud = su[k][s3];
            float vk = vreg[k], wk = wrreg[k];
            float m1a = fmaxf(fmaf(r2a, wk, ua + vk), 0.f);
            float m1b = fmaxf(fmaf(r2b, wk, ub + vk), 0.f);
            float m1c = fmaxf(fmaf(r2c, wk, uc + vk), 0.f);
            float m1d = fmaxf(fmaf(r2d, wk, ud + vk), 0.f);
            float wrow[NF];
#pragma unroll
            for (int q = 0; q < 4; ++q) {
                float4 w = We2v[k * 4 + q];
                wrow[q * 4 + 0] = w.x; wrow[q * 4 + 1] = w.y;
                wrow[q * 4 + 2] = w.z; wrow[q * 4 + 3] = w.w;
            }
#pragma unroll
            for (int o = 0; o < NF; ++o) {
                ma[o] = fmaf(m1a, wrow[o], ma[o]);
                mb[o] = fmaf(m1b, wrow[o], mb[o]);
                mc[o] = fmaf(m1c, wrow[o], mc[o]);
                md[o] = fmaf(m1d, wrow[o], md[o]);
            }
        }
        float wA = 0.f, wB = 0.f, wC = 0.f, wD = 0.f;
#pragma unroll
        for (int o = 0; o < NF; ++o) {
            float xo = sWx[o];
            ma[o] = fmaxf(ma[o], 0.f);
            mb[o] = fmaxf(mb[o], 0.f);
            mc[o] = fmaxf(mc[o], 0.f);
            md[o] = fmaxf(md[o], 0.f);
            wA = fmaf(ma[o], xo, wA);
            wB = fmaf(mb[o], xo, wB);
            wC = fmaf(mc[o], xo, wC);
            wD = fmaf(md[o], xo, wD);
            aggm[o] = fmaf(ma[o], vala, aggm[o]);
            aggm[o] = fmaf(mb[o], valb, aggm[o]);
            aggm[o] = fmaf(mc[o], valc, aggm[o]);
            aggm[o] = fmaf(md[o], vald, aggm[o]);
        }
        ax = fmaf(wA, dax, fmaf(wB, dbx, fmaf(wC, dcx, fmaf(wD, ddx, ax))));
        ay = fmaf(wA, day, fmaf(wB, dby, fmaf(wC, dcy, fmaf(wD, ddy, ay))));
        az = fmaf(wA, daz, fmaf(wB, dbz, fmaf(wC, dcz, fmaf(wD, ddz, az))));
    }

    // ---- reduce across the 16 lanes of this dst group (butterfly) ----
#pragma unroll
    for (int off = 1; off < 16; off <<= 1) {
#pragma unroll
        for (int o = 0; o < NF; ++o) aggm[o] += __shfl_xor(aggm[o], off, 64);
        ax += __shfl_xor(ax, off, 64);
        ay += __shfl_xor(ay, off, 64);
        az += __shfl_xor(az, off, 64);
    }

    // ---- node updates ----
    float hj[NF];
#pragma unroll
    for (int k = 0; k < NF; ++k) hj[k] = sh[j][k];

    float hv = 0.f;
#pragma unroll
    for (int k = 0; k < NF; ++k) hv = fmaf(hj[k], sWv[k], hv);

    // h update: this lane computes feature f = sl
    float hd = sbh1[sl];
#pragma unroll
    for (int k = 0; k < NF; ++k) hd = fmaf(hj[k], sWh1[k][sl], hd);
#pragma unroll
    for (int k = 0; k < NF; ++k) hd = fmaf(aggm[k], sWh1[NF + k][sl], hd);
    float hnew = hj[sl] + fmaxf(hd, 0.f);
    h_out[((size_t)b * NN + j) * NF + sl] = hnew;

    if (sl < 3) {
        float vcomp = vs[((size_t)b * NN + j) * 3 + sl];
        float xc = (sl == 0) ? xj.x : ((sl == 1) ? xj.y : xj.z);
        float ac = (sl == 0) ? ax : ((sl == 1) ? ay : az);
        float xnew = fmaf(ac, (1.f / 255.f), fmaf(vcomp, hv, xc));
        if (final_layer) x_out[((size_t)b * NN + j) * 3 + sl] = xnew;
        else             x_out[((size_t)b * NN + j) * 4 + sl] = xnew;
    }
    if (!final_layer && sl == 3) x_out[((size_t)b * NN + j) * 4 + 3] = 0.f;
}

extern "C" void kernel_launch(void* const* d_in, const int* in_sizes, int n_in,
                              void* d_out, int out_size, void* d_ws, size_t ws_size,
                              hipStream_t stream) {
    const float* xs      = (const float*)d_in[0];
    const float* vs      = (const float*)d_in[1];
    const float* charges = (const float*)d_in[2];
    const float* W_in    = (const float*)d_in[3];
    const float* b_in    = (const float*)d_in[4];
    const float* W_v     = (const float*)d_in[5];
    const float* We1     = (const float*)d_in[6];
    const float* be1     = (const float*)d_in[7];
    const float* We2     = (const float*)d_in[8];
    const float* be2     = (const float*)d_in[9];
    const float* Wx      = (const float*)d_in[10];
    const float* Wh1     = (const float*)d_in[11];
    const float* bh1     = (const float*)d_in[12];
    // d_in[13]=src, d_in[14]=dst: fully-connected pattern, computed analytically.

    float* ws = (float*)d_ws;
    float* x0 = ws;
    float* x1 = ws + 32768;
    float* h0 = ws + 65536;
    float* h1 = ws + 196608;
    float* out = (float*)d_out;

    hipLaunchKernelGGL(init_kernel, dim3(32), dim3(256), 0, stream,
                       xs, charges, W_in, b_in, x0, h0);
    hipLaunchKernelGGL(layer_kernel, dim3(512), dim3(256), 0, stream,
                       x0, h0, x1, h1, vs, W_v, We1, be1, We2, be2, Wx, Wh1, bh1, 0, 0);
    hipLaunchKernelGGL(layer_kernel, dim3(512), dim3(256), 0, stream,
                       x1, h1, x0, h0, vs, W_v, We1, be1, We2, be2, Wx, Wh1, bh1, 1, 0);
    hipLaunchKernelGGL(layer_kernel, dim3(512), dim3(256), 0, stream,
                       x0, h0, out, h1, vs, W_v, We1, be1, We2, be2, Wx, Wh1, bh1, 2, 1);
}